// Round 11
// baseline (453.391 us; speedup 1.0000x reference)
//
#include <hip/hip_runtime.h>
#include <math.h>

#define NN 100000
#define NE 1600000
#define DI 256
#define DH 64
#define DO 47
#define DH3 48                      // h3s row stride: 192B -> 19.2 MB footprint
#define NB ((NN + 255) / 256)       // 391 scan blocks
#define RSZ8 ((NN + 7) / 8)         // 12500 nodes per XCD-pinned range
#define EPB 2048                    // edges per fill block
#define CPB ((NE + EPB - 1) / EPB)  // 782 chunks per range

typedef float f8 __attribute__((ext_vector_type(8)));

// ---------------- degree, XCD-pinned ranges ----------------
__global__ __launch_bounds__(256) void k_degree(const int* __restrict__ dst,
                                                int* __restrict__ deg) {
    int r = blockIdx.x & 7;
    int chunk = blockIdx.x >> 3;
    int lo = r * RSZ8, hi = min(lo + RSZ8, NN);
    int base = chunk * EPB + threadIdx.x;
    #pragma unroll
    for (int i = 0; i < EPB / 256; ++i) {
        int e = base + i * 256;
        if (e < NE) {
            int d = dst[e];
            if (d >= lo && d < hi) atomicAdd(&deg[d], 1);
        }
    }
}

// ---------------- scan pass 1: per-block sums of deg ----------------
__global__ __launch_bounds__(256) void k_part(const int* __restrict__ deg,
                                              int* __restrict__ part) {
    int i = blockIdx.x * 256 + threadIdx.x;
    int v = (i < NN) ? deg[i] : 0;
    for (int off = 32; off; off >>= 1) v += __shfl_xor(v, off);
    __shared__ int s[4];
    if ((threadIdx.x & 63) == 0) s[threadIdx.x >> 6] = v;
    __syncthreads();
    if (threadIdx.x == 0) part[blockIdx.x] = s[0] + s[1] + s[2] + s[3];
}

// ---------------- scan pass 2: exclusive scan of partials (NB<=512) ----------------
__global__ __launch_bounds__(512) void k_scanpart(int* __restrict__ part) {
    int t = threadIdx.x, lane = t & 63, wv = t >> 6;
    int v0 = (t < NB) ? part[t] : 0;
    int v = v0;
    for (int off = 1; off < 64; off <<= 1) {
        int u = __shfl_up(v, off);
        if (lane >= off) v += u;
    }
    __shared__ int ws[8];
    if (lane == 63) ws[wv] = v;
    __syncthreads();
    if (t == 0) {
        int run = 0;
        for (int w = 0; w < 8; ++w) { int tmp = ws[w]; ws[w] = run; run += tmp; }
    }
    __syncthreads();
    v += ws[wv];
    if (t < NB) part[t] = v - v0;   // exclusive
}

// ---------------- scan pass 3: prefix -> rowptr, cursor; fused dinv ----------------
__global__ __launch_bounds__(256) void k_scan3(const int* __restrict__ deg,
                                               const int* __restrict__ part,
                                               int* __restrict__ rowptr,
                                               int* __restrict__ cursor,
                                               float* __restrict__ dinv) {
    int i = blockIdx.x * 256 + threadIdx.x;
    int lane = threadIdx.x & 63, wv = threadIdx.x >> 6;
    int v0 = (i < NN) ? deg[i] : 0;
    int v = v0;
    for (int off = 1; off < 64; off <<= 1) {
        int u = __shfl_up(v, off);
        if (lane >= off) v += u;
    }
    __shared__ int ws[4], wo[4];
    if (lane == 63) ws[wv] = v;
    __syncthreads();
    if (threadIdx.x == 0) {
        int run = 0;
        for (int w = 0; w < 4; ++w) { int tmp = ws[w]; wo[w] = run; run += tmp; }
    }
    __syncthreads();
    int excl = part[blockIdx.x] + wo[wv] + v - v0;
    if (i < NN) {
        rowptr[i] = excl;
        cursor[i] = excl;
        dinv[i] = rsqrtf((float)(v0 + 1));
    }
}

// ---------------- bucket-fill, XCD-pinned ranges ----------------
__global__ __launch_bounds__(256) void k_fillr(const int* __restrict__ src,
                                               const int* __restrict__ dst,
                                               int* __restrict__ cursor,
                                               int* __restrict__ csr_src) {
    int r = blockIdx.x & 7;
    int chunk = blockIdx.x >> 3;
    int lo = r * RSZ8, hi = min(lo + RSZ8, NN);
    int base = chunk * EPB + threadIdx.x;
    #pragma unroll
    for (int i = 0; i < EPB / 256; ++i) {
        int e = base + i * 256;
        if (e < NE) {
            int d = dst[e];
            if (d >= lo && d < hi) {
                int p = atomicAdd(&cursor[d], 1);
                csr_src[p] = src[e];
            }
        }
    }
}

// ---------------- h1s = dinv * (x @ W1)  (N x 256 x 64), fp32 ----------------
// Pure-DS inner loop: x tile AND W1 chunk both staged in LDS (double-buffered).
// No SMEM in the k-loop -> in-order DS returns -> fine-grained lgkmcnt pipelining.
// 512 thr, lane = row; wave w owns cols [8w,8w+8); w8 = uniform b128 broadcasts.
__global__ __launch_bounds__(512) void k_gemm1(const float* __restrict__ x,
                                               const float* __restrict__ W1,
                                               const float* __restrict__ dinv,
                                               float* __restrict__ h1s) {
    __shared__ float xs[2][64 * 33];   // 16.9 KB
    __shared__ float wl[2][32 * 64];   // 16 KB
    const int t = threadIdx.x;
    const int lane = t & 63;
    const int wvu = __builtin_amdgcn_readfirstlane(t >> 6);
    const int r0 = blockIdx.x * 64;
    const int sr = t >> 3;             // x staging: 8 threads/row
    const int sk = (t & 7) * 4;        // float4 each
    const int wk = t >> 4;             // W staging: row in chunk (0..31)
    const int wc = (t & 15) * 4;       // col quad
    const long xrow = (long)min(r0 + sr, NN - 1) * DI;
    const int row = r0 + lane;

    float acc[8] = {0.f, 0.f, 0.f, 0.f, 0.f, 0.f, 0.f, 0.f};

    {   // stage chunk 0
        float4 v = *(const float4*)(x + xrow + sk);
        float* p = &xs[0][sr * 33 + sk];
        p[0] = v.x; p[1] = v.y; p[2] = v.z; p[3] = v.w;
        float4 w = *(const float4*)(W1 + (size_t)wk * DH + wc);
        float* q = &wl[0][wk * 64 + wc];
        q[0] = w.x; q[1] = w.y; q[2] = w.z; q[3] = w.w;
    }
    __syncthreads();
    for (int c = 0; c < 8; ++c) {
        const int buf = c & 1;
        if (c + 1 < 8) {   // prefetch next 32-k chunk (x + W) into other buffer
            float4 v = *(const float4*)(x + xrow + (c + 1) * 32 + sk);
            float* p = &xs[buf ^ 1][sr * 33 + sk];
            p[0] = v.x; p[1] = v.y; p[2] = v.z; p[3] = v.w;
            float4 w = *(const float4*)(W1 + (size_t)((c + 1) * 32 + wk) * DH + wc);
            float* q = &wl[buf ^ 1][wk * 64 + wc];
            q[0] = w.x; q[1] = w.y; q[2] = w.z; q[3] = w.w;
        }
        #pragma unroll
        for (int k = 0; k < 32; ++k) {
            float xv = xs[buf][lane * 33 + k];
            f8 w8 = *(const f8*)&wl[buf][k * 64 + wvu * 8];
            #pragma unroll
            for (int j = 0; j < 8; ++j) acc[j] += w8[j] * xv;
        }
        __syncthreads();
    }
    if (row < NN) {
        float di = dinv[row];
        float4 o0 = {di * acc[0], di * acc[1], di * acc[2], di * acc[3]};
        float4 o1 = {di * acc[4], di * acc[5], di * acc[6], di * acc[7]};
        float4* hp = (float4*)(h1s + (long)row * DH + wvu * 8);
        hp[0] = o0;
        hp[1] = o1;
    }
}

// ---------------- layer1 gather (4 rows/wave) + relu/bias + GEMM2 fused ----------------
__global__ __launch_bounds__(256) void k_agg1(const int* __restrict__ rowptr,
                                              const int* __restrict__ deg,
                                              const int* __restrict__ csr_src,
                                              const float* __restrict__ dinv,
                                              const float* __restrict__ h1s,
                                              const float* __restrict__ b1,
                                              const float* __restrict__ W2,
                                              float* __restrict__ h3s) {
    __shared__ float w2[DH * DO];   // 12 KB
    __shared__ float sh[16][DH];    // 4 KB
    for (int i = threadIdx.x; i < DH * DO; i += 256) w2[i] = W2[i];
    __syncthreads();
    const int wv = threadIdx.x >> 6, lane = threadIdx.x & 63;
    const int rbase = blockIdx.x * 16 + wv * 4;
    int beg[4], cnt[4];
    float acc[4] = {0.f, 0.f, 0.f, 0.f};
    #pragma unroll
    for (int r = 0; r < 4; ++r) {
        beg[r] = rowptr[rbase + r];
        cnt[r] = deg[rbase + r];
    }
    const int tmax = max(max(cnt[0], cnt[1]), max(cnt[2], cnt[3]));
    for (int j = 0; j < tmax; j += 4) {
        #pragma unroll
        for (int k = 0; k < 4; ++k) {
            #pragma unroll
            for (int r = 0; r < 4; ++r) {
                int s = csr_src[min(beg[r] + j + k, NE - 1)];
                float v = h1s[(size_t)s * DH + lane];
                acc[r] += (j + k < cnt[r]) ? v : 0.f;
            }
        }
    }
    float di[4];
    #pragma unroll
    for (int r = 0; r < 4; ++r) {
        di[r] = dinv[rbase + r];
        float v = di[r] * (acc[r] + h1s[(size_t)(rbase + r) * DH + lane]) + b1[lane];
        sh[wv * 4 + r][lane] = fmaxf(v, 0.f);
    }
    __syncthreads();
    if (lane < DO) {
        float o[4] = {0.f, 0.f, 0.f, 0.f};
        #pragma unroll 8
        for (int k = 0; k < DH; ++k) {
            float w = w2[k * DO + lane];
            #pragma unroll
            for (int r = 0; r < 4; ++r) o[r] += sh[wv * 4 + r][k] * w;
        }
        #pragma unroll
        for (int r = 0; r < 4; ++r)
            h3s[(size_t)(rbase + r) * DH3 + lane] = di[r] * o[r];
    }
}

// ---------------- layer2 gather (4 rows/wave) + softmax/argmax fused ----------------
__global__ __launch_bounds__(256) void k_agg2(const int* __restrict__ rowptr,
                                              const int* __restrict__ deg,
                                              const int* __restrict__ csr_src,
                                              const float* __restrict__ dinv,
                                              const float* __restrict__ h3s,
                                              const float* __restrict__ b2,
                                              float* __restrict__ logits,
                                              float* __restrict__ preds,
                                              float* __restrict__ xo) {
    const int wv = threadIdx.x >> 6, lane = threadIdx.x & 63;
    const int rbase = blockIdx.x * 16 + wv * 4;
    const bool act = lane < DO;
    const int lx = act ? lane : 0;
    int beg[4], cnt[4];
    float acc[4] = {0.f, 0.f, 0.f, 0.f};
    #pragma unroll
    for (int r = 0; r < 4; ++r) {
        beg[r] = rowptr[rbase + r];
        cnt[r] = deg[rbase + r];
    }
    const int tmax = max(max(cnt[0], cnt[1]), max(cnt[2], cnt[3]));
    for (int j = 0; j < tmax; j += 4) {
        #pragma unroll
        for (int k = 0; k < 4; ++k) {
            #pragma unroll
            for (int r = 0; r < 4; ++r) {
                int s = csr_src[min(beg[r] + j + k, NE - 1)];
                float v = h3s[(size_t)s * DH3 + lx];
                acc[r] += (j + k < cnt[r]) ? v : 0.f;
            }
        }
    }
    float val[4];
    #pragma unroll
    for (int r = 0; r < 4; ++r) {
        float di = dinv[rbase + r];
        val[r] = act ? di * (acc[r] + h3s[(size_t)(rbase + r) * DH3 + lane]) + b2[lane]
                     : -INFINITY;
        if (act) xo[(size_t)(rbase + r) * DO + lane] = val[r];
    }
    float m[4] = {val[0], val[1], val[2], val[3]};
    for (int off = 32; off; off >>= 1) {
        #pragma unroll
        for (int r = 0; r < 4; ++r) m[r] = fmaxf(m[r], __shfl_xor(m[r], off));
    }
    int idx[4];
    #pragma unroll
    for (int r = 0; r < 4; ++r) idx[r] = (act && val[r] == m[r]) ? lane : (1 << 30);
    for (int off = 32; off; off >>= 1) {
        #pragma unroll
        for (int r = 0; r < 4; ++r) idx[r] = min(idx[r], __shfl_xor(idx[r], off));
    }
    float ev[4], ss[4];
    #pragma unroll
    for (int r = 0; r < 4; ++r) { ev[r] = act ? expf(val[r] - m[r]) : 0.f; ss[r] = ev[r]; }
    for (int off = 32; off; off >>= 1) {
        #pragma unroll
        for (int r = 0; r < 4; ++r) ss[r] += __shfl_xor(ss[r], off);
    }
    if (act) {
        #pragma unroll
        for (int r = 0; r < 4; ++r)
            logits[(size_t)(rbase + r) * DO + lane] = ev[r] / ss[r];
    }
    if (lane == 0) {
        #pragma unroll
        for (int r = 0; r < 4; ++r) preds[rbase + r] = (float)idx[r];
    }
}

extern "C" void kernel_launch(void* const* d_in, const int* in_sizes, int n_in,
                              void* d_out, int out_size, void* d_ws, size_t ws_size,
                              hipStream_t stream) {
    const float* x  = (const float*)d_in[0];
    const int*   ei = (const int*)d_in[1];
    const float* W1 = (const float*)d_in[2];
    const float* b1 = (const float*)d_in[3];
    const float* W2 = (const float*)d_in[4];
    const float* b2 = (const float*)d_in[5];
    const int* src = ei;          // edge_index[0]
    const int* dst = ei + NE;     // edge_index[1]

    float* out    = (float*)d_out;
    float* logits = out;                      // [N,47]
    float* preds  = out + (size_t)NN * DO;    // [N]
    float* xo     = preds + NN;               // [N,47]

    // workspace layout (~53 MB)
    char* wsb = (char*)d_ws;
    int*   deg     = (int*)wsb;                         wsb += (size_t)NN * 4;
    float* dinv    = (float*)wsb;                       wsb += (size_t)NN * 4;
    int*   rowptr  = (int*)wsb;                         wsb += (size_t)NN * 4;
    int*   cursor  = (int*)wsb;                         wsb += (size_t)NN * 4;
    int*   part    = (int*)wsb;                         wsb += (size_t)512 * 4;
    int*   csr_src = (int*)wsb;                         wsb += (size_t)NE * 4;
    float* h1s     = (float*)wsb;                       wsb += (size_t)NN * DH * 4;
    float* h3s     = (float*)wsb;                       wsb += (size_t)NN * DH3 * 4;

    hipMemsetAsync(deg, 0, NN * sizeof(int), stream);

    k_degree<<<8 * CPB, 256, 0, stream>>>(dst, deg);
    k_part<<<NB, 256, 0, stream>>>(deg, part);
    k_scanpart<<<1, 512, 0, stream>>>(part);
    k_scan3<<<NB, 256, 0, stream>>>(deg, part, rowptr, cursor, dinv);
    k_fillr<<<8 * CPB, 256, 0, stream>>>(src, dst, cursor, csr_src);
    k_gemm1<<<(NN + 63) / 64, 512, 0, stream>>>(x, W1, dinv, h1s);
    k_agg1<<<NN / 16, 256, 0, stream>>>(rowptr, deg, csr_src, dinv, h1s, b1, W2, h3s);
    k_agg2<<<NN / 16, 256, 0, stream>>>(rowptr, deg, csr_src, dinv, h3s, b2, logits, preds, xo);
}

// Round 12
// 355.758 us; speedup vs baseline: 1.2744x; 1.2744x over previous
//
#include <hip/hip_runtime.h>
#include <math.h>

#define NN 100000
#define NE 1600000
#define DI 256
#define DH 64
#define DO 47
#define DH3 48                      // h3s row stride: 192B -> 19.2 MB footprint
#define NB ((NN + 255) / 256)       // 391 scan blocks
#define RSZ8 ((NN + 7) / 8)         // 12500 nodes per XCD-pinned range
#define EPB 2048                    // edges per fill block
#define CPB ((NE + EPB - 1) / EPB)  // 782 chunks per range

typedef float f8 __attribute__((ext_vector_type(8)));

// ---------------- degree, XCD-pinned ranges ----------------
__global__ __launch_bounds__(256) void k_degree(const int* __restrict__ dst,
                                                int* __restrict__ deg) {
    int r = blockIdx.x & 7;
    int chunk = blockIdx.x >> 3;
    int lo = r * RSZ8, hi = min(lo + RSZ8, NN);
    int base = chunk * EPB + threadIdx.x;
    #pragma unroll
    for (int i = 0; i < EPB / 256; ++i) {
        int e = base + i * 256;
        if (e < NE) {
            int d = dst[e];
            if (d >= lo && d < hi) atomicAdd(&deg[d], 1);
        }
    }
}

// ---------------- scan pass 1: per-block sums of deg ----------------
__global__ __launch_bounds__(256) void k_part(const int* __restrict__ deg,
                                              int* __restrict__ part) {
    int i = blockIdx.x * 256 + threadIdx.x;
    int v = (i < NN) ? deg[i] : 0;
    for (int off = 32; off; off >>= 1) v += __shfl_xor(v, off);
    __shared__ int s[4];
    if ((threadIdx.x & 63) == 0) s[threadIdx.x >> 6] = v;
    __syncthreads();
    if (threadIdx.x == 0) part[blockIdx.x] = s[0] + s[1] + s[2] + s[3];
}

// ---------------- scan pass 2: exclusive scan of partials (NB<=512) ----------------
__global__ __launch_bounds__(512) void k_scanpart(int* __restrict__ part) {
    int t = threadIdx.x, lane = t & 63, wv = t >> 6;
    int v0 = (t < NB) ? part[t] : 0;
    int v = v0;
    for (int off = 1; off < 64; off <<= 1) {
        int u = __shfl_up(v, off);
        if (lane >= off) v += u;
    }
    __shared__ int ws[8];
    if (lane == 63) ws[wv] = v;
    __syncthreads();
    if (t == 0) {
        int run = 0;
        for (int w = 0; w < 8; ++w) { int tmp = ws[w]; ws[w] = run; run += tmp; }
    }
    __syncthreads();
    v += ws[wv];
    if (t < NB) part[t] = v - v0;   // exclusive
}

// ---------------- scan pass 3: prefix -> rowptr, cursor; fused dinv ----------------
__global__ __launch_bounds__(256) void k_scan3(const int* __restrict__ deg,
                                               const int* __restrict__ part,
                                               int* __restrict__ rowptr,
                                               int* __restrict__ cursor,
                                               float* __restrict__ dinv) {
    int i = blockIdx.x * 256 + threadIdx.x;
    int lane = threadIdx.x & 63, wv = threadIdx.x >> 6;
    int v0 = (i < NN) ? deg[i] : 0;
    int v = v0;
    for (int off = 1; off < 64; off <<= 1) {
        int u = __shfl_up(v, off);
        if (lane >= off) v += u;
    }
    __shared__ int ws[4], wo[4];
    if (lane == 63) ws[wv] = v;
    __syncthreads();
    if (threadIdx.x == 0) {
        int run = 0;
        for (int w = 0; w < 4; ++w) { int tmp = ws[w]; wo[w] = run; run += tmp; }
    }
    __syncthreads();
    int excl = part[blockIdx.x] + wo[wv] + v - v0;
    if (i < NN) {
        rowptr[i] = excl;
        cursor[i] = excl;
        dinv[i] = rsqrtf((float)(v0 + 1));
    }
}

// ---------------- bucket-fill, XCD-pinned ranges ----------------
__global__ __launch_bounds__(256) void k_fillr(const int* __restrict__ src,
                                               const int* __restrict__ dst,
                                               int* __restrict__ cursor,
                                               int* __restrict__ csr_src) {
    int r = blockIdx.x & 7;
    int chunk = blockIdx.x >> 3;
    int lo = r * RSZ8, hi = min(lo + RSZ8, NN);
    int base = chunk * EPB + threadIdx.x;
    #pragma unroll
    for (int i = 0; i < EPB / 256; ++i) {
        int e = base + i * 256;
        if (e < NE) {
            int d = dst[e];
            if (d >= lo && d < hi) {
                int p = atomicAdd(&cursor[d], 1);
                csr_src[p] = src[e];
            }
        }
    }
}

// ---------------- h1s = dinv * (x @ W1)  (N x 256 x 64), fp32 ----------------
// T14 async-STAGE split, 2-deep: issue load chunk c+2 -> compute chunk c from
// LDS -> vmcnt-wait + ds_write chunk c+1 -> ONE barrier. Load has ~2 compute
// phases to land; ds_write waits vmcnt(1), never a full drain.
// W1 stays wave-uniform s_load (low VGPR, L2-resident).
__global__ __launch_bounds__(512) void k_gemm1(const float* __restrict__ x,
                                               const float* __restrict__ W1,
                                               const float* __restrict__ dinv,
                                               float* __restrict__ h1s) {
    __shared__ float xs[2][64 * 33];   // 16.9 KB, stride-33: 2-way bank alias (free)
    const int t = threadIdx.x;
    const int lane = t & 63;
    const int wvu = __builtin_amdgcn_readfirstlane(t >> 6);
    const int r0 = blockIdx.x * 64;
    const int sr = t >> 3;             // staging: 8 threads per row
    const int sk = (t & 7) * 4;        // float4 each
    const long xrow = (long)min(r0 + sr, NN - 1) * DI;
    const int row = r0 + lane;

    float acc[8] = {0.f, 0.f, 0.f, 0.f, 0.f, 0.f, 0.f, 0.f};

    // prologue: chunks 0,1 -> registers; chunk 0 -> LDS
    float4 pf1;
    {
        float4 pf0 = *(const float4*)(x + xrow + 0 * 32 + sk);
        pf1 = *(const float4*)(x + xrow + 1 * 32 + sk);
        float* p = &xs[0][sr * 33 + sk];
        p[0] = pf0.x; p[1] = pf0.y; p[2] = pf0.z; p[3] = pf0.w;
    }
    __syncthreads();
    for (int c = 0; c < 8; ++c) {
        const int buf = c & 1;
        float4 pfn;
        if (c + 2 < 8)   // 1. issue load chunk c+2 (stays in flight through compute)
            pfn = *(const float4*)(x + xrow + (c + 2) * 32 + sk);
        // 2. compute chunk c from xs[buf]
        const f8* wp = (const f8*)(W1) + (size_t)(c * 32) * (DH / 8) + wvu;
        #pragma unroll
        for (int k = 0; k < 32; ++k) {
            float xv = xs[buf][lane * 33 + k];
            f8 w8 = wp[(size_t)k * (DH / 8)];
            #pragma unroll
            for (int j = 0; j < 8; ++j) acc[j] += w8[j] * xv;
        }
        // 3. write chunk c+1 into other buffer (vmcnt(1): only pfn still pending)
        if (c + 1 < 8) {
            float* p = &xs[buf ^ 1][sr * 33 + sk];
            p[0] = pf1.x; p[1] = pf1.y; p[2] = pf1.z; p[3] = pf1.w;
        }
        __syncthreads();           // 4. chunk c+1 visible; gates next iter's writes
        pf1 = pfn;
    }
    if (row < NN) {
        float di = dinv[row];
        float4 o0 = {di * acc[0], di * acc[1], di * acc[2], di * acc[3]};
        float4 o1 = {di * acc[4], di * acc[5], di * acc[6], di * acc[7]};
        float4* hp = (float4*)(h1s + (long)row * DH + wvu * 8);
        hp[0] = o0;
        hp[1] = o1;
    }
}

// ---------------- layer1 gather (2 rows/wave) + relu/bias + GEMM2 fused ----------------
__global__ __launch_bounds__(256) void k_agg1(const int* __restrict__ rowptr,
                                              const int* __restrict__ deg,
                                              const int* __restrict__ csr_src,
                                              const float* __restrict__ dinv,
                                              const float* __restrict__ h1s,
                                              const float* __restrict__ b1,
                                              const float* __restrict__ W2,
                                              float* __restrict__ h3s) {
    __shared__ float w2[DH * DO];   // 12 KB
    __shared__ float sh[8][DH];     // 2 KB
    for (int i = threadIdx.x; i < DH * DO; i += 256) w2[i] = W2[i];
    __syncthreads();
    const int wv = threadIdx.x >> 6, lane = threadIdx.x & 63;
    const int rA = blockIdx.x * 8 + wv * 2;
    const int rB = rA + 1;
    const int begA = rowptr[rA], cntA = deg[rA];
    const int begB = rowptr[rB], cntB = deg[rB];
    float accA = 0.f, accB = 0.f;
    const int tmax = max(cntA, cntB);
    #pragma unroll 2
    for (int j = 0; j < tmax; j += 4) {
        #pragma unroll
        for (int k = 0; k < 4; ++k) {
            int sa = csr_src[min(begA + j + k, NE - 1)];
            int sb = csr_src[min(begB + j + k, NE - 1)];
            float va = h1s[(size_t)sa * DH + lane];
            float vb = h1s[(size_t)sb * DH + lane];
            accA += (j + k < cntA) ? va : 0.f;
            accB += (j + k < cntB) ? vb : 0.f;
        }
    }
    const float diA = dinv[rA], diB = dinv[rB];
    float vA = diA * (accA + h1s[(size_t)rA * DH + lane]) + b1[lane];
    float vB = diB * (accB + h1s[(size_t)rB * DH + lane]) + b1[lane];
    sh[wv * 2 + 0][lane] = fmaxf(vA, 0.f);
    sh[wv * 2 + 1][lane] = fmaxf(vB, 0.f);
    __syncthreads();
    if (lane < DO) {
        float oA = 0.f, oB = 0.f;
        #pragma unroll 8
        for (int k = 0; k < DH; ++k) {
            float w = w2[k * DO + lane];
            oA += sh[wv * 2 + 0][k] * w;
            oB += sh[wv * 2 + 1][k] * w;
        }
        h3s[(size_t)rA * DH3 + lane] = diA * oA;
        h3s[(size_t)rB * DH3 + lane] = diB * oB;
    }
}

// ---------------- layer2 gather (2 rows/wave) + softmax/argmax fused ----------------
__global__ __launch_bounds__(256) void k_agg2(const int* __restrict__ rowptr,
                                              const int* __restrict__ deg,
                                              const int* __restrict__ csr_src,
                                              const float* __restrict__ dinv,
                                              const float* __restrict__ h3s,
                                              const float* __restrict__ b2,
                                              float* __restrict__ logits,
                                              float* __restrict__ preds,
                                              float* __restrict__ xo) {
    const int wv = threadIdx.x >> 6, lane = threadIdx.x & 63;
    const int rA = blockIdx.x * 8 + wv * 2;
    const int rB = rA + 1;
    const int begA = rowptr[rA], cntA = deg[rA];
    const int begB = rowptr[rB], cntB = deg[rB];
    const bool act = lane < DO;
    const int lx = act ? lane : 0;
    float accA = 0.f, accB = 0.f;
    const int tmax = max(cntA, cntB);
    #pragma unroll 2
    for (int j = 0; j < tmax; j += 4) {
        #pragma unroll
        for (int k = 0; k < 4; ++k) {
            int sa = csr_src[min(begA + j + k, NE - 1)];
            int sb = csr_src[min(begB + j + k, NE - 1)];
            float va = h3s[(size_t)sa * DH3 + lx];
            float vb = h3s[(size_t)sb * DH3 + lx];
            accA += (j + k < cntA) ? va : 0.f;
            accB += (j + k < cntB) ? vb : 0.f;
        }
    }
    const float diA = dinv[rA], diB = dinv[rB];
    float valA = -INFINITY, valB = -INFINITY;
    if (act) {
        valA = diA * (accA + h3s[(size_t)rA * DH3 + lane]) + b2[lane];
        valB = diB * (accB + h3s[(size_t)rB * DH3 + lane]) + b2[lane];
        xo[(size_t)rA * DO + lane] = valA;
        xo[(size_t)rB * DO + lane] = valB;
    }
    float mA = valA, mB = valB;
    for (int off = 32; off; off >>= 1) {
        mA = fmaxf(mA, __shfl_xor(mA, off));
        mB = fmaxf(mB, __shfl_xor(mB, off));
    }
    int idxA = (act && valA == mA) ? lane : (1 << 30);
    int idxB = (act && valB == mB) ? lane : (1 << 30);
    for (int off = 32; off; off >>= 1) {
        idxA = min(idxA, __shfl_xor(idxA, off));
        idxB = min(idxB, __shfl_xor(idxB, off));
    }
    float evA = act ? expf(valA - mA) : 0.f;
    float evB = act ? expf(valB - mB) : 0.f;
    float sA = evA, sB = evB;
    for (int off = 32; off; off >>= 1) {
        sA += __shfl_xor(sA, off);
        sB += __shfl_xor(sB, off);
    }
    if (act) {
        logits[(size_t)rA * DO + lane] = evA / sA;
        logits[(size_t)rB * DO + lane] = evB / sB;
    }
    if (lane == 0) {
        preds[rA] = (float)idxA;
        preds[rB] = (float)idxB;
    }
}

extern "C" void kernel_launch(void* const* d_in, const int* in_sizes, int n_in,
                              void* d_out, int out_size, void* d_ws, size_t ws_size,
                              hipStream_t stream) {
    const float* x  = (const float*)d_in[0];
    const int*   ei = (const int*)d_in[1];
    const float* W1 = (const float*)d_in[2];
    const float* b1 = (const float*)d_in[3];
    const float* W2 = (const float*)d_in[4];
    const float* b2 = (const float*)d_in[5];
    const int* src = ei;          // edge_index[0]
    const int* dst = ei + NE;     // edge_index[1]

    float* out    = (float*)d_out;
    float* logits = out;                      // [N,47]
    float* preds  = out + (size_t)NN * DO;    // [N]
    float* xo     = preds + NN;               // [N,47]

    // workspace layout (~53 MB)
    char* wsb = (char*)d_ws;
    int*   deg     = (int*)wsb;                         wsb += (size_t)NN * 4;
    float* dinv    = (float*)wsb;                       wsb += (size_t)NN * 4;
    int*   rowptr  = (int*)wsb;                         wsb += (size_t)NN * 4;
    int*   cursor  = (int*)wsb;                         wsb += (size_t)NN * 4;
    int*   part    = (int*)wsb;                         wsb += (size_t)512 * 4;
    int*   csr_src = (int*)wsb;                         wsb += (size_t)NE * 4;
    float* h1s     = (float*)wsb;                       wsb += (size_t)NN * DH * 4;
    float* h3s     = (float*)wsb;                       wsb += (size_t)NN * DH3 * 4;

    hipMemsetAsync(deg, 0, NN * sizeof(int), stream);

    k_degree<<<8 * CPB, 256, 0, stream>>>(dst, deg);
    k_part<<<NB, 256, 0, stream>>>(deg, part);
    k_scanpart<<<1, 512, 0, stream>>>(part);
    k_scan3<<<NB, 256, 0, stream>>>(deg, part, rowptr, cursor, dinv);
    k_fillr<<<8 * CPB, 256, 0, stream>>>(src, dst, cursor, csr_src);
    k_gemm1<<<(NN + 63) / 64, 512, 0, stream>>>(x, W1, dinv, h1s);
    k_agg1<<<NN / 8, 256, 0, stream>>>(rowptr, deg, csr_src, dinv, h1s, b1, W2, h3s);
    k_agg2<<<NN / 8, 256, 0, stream>>>(rowptr, deg, csr_src, dinv, h3s, b2, logits, preds, xo);
}